// Round 1
// 1554.848 us; speedup vs baseline: 1.0193x; 1.0193x over previous
//
#include <hip/hip_runtime.h>
#include <math.h>

#define BATCH 8
#define WID   32
#define NX    64
#define NY    64
#define NT    40
#define M1C   12
#define KT    8      // M3
#define KXC   24
#define KYC   24
#define NXY   (NX*NY)        // 4096
#define NXYT  (NXY*NT)       // 163840
#define NP    (BATCH*NXYT)   // 1310720

#define TWO_PI 6.283185307179586f

static __device__ __forceinline__ float gelu_f(float v){
  return 0.5f*v*(1.0f + erff(v*0.7071067811865476f));
}

// barrier that does NOT drain vmcnt (keeps global prefetch loads in flight).
static __device__ __forceinline__ void barrier_lds(){
  asm volatile("s_waitcnt lgkmcnt(0)\n\ts_barrier" ::: "memory");
}

// V layout throughout: [b][x][y][t][c]  (channel-innermost, plane = 1280 floats)

// ---------------- fc0: [B,X,Y,T,5] -> V ----------------
__global__ __launch_bounds__(256) void k_fc0(const float* __restrict__ h, const float* __restrict__ x,
                                             const float* __restrict__ w, const float* __restrict__ b,
                                             float* __restrict__ V){
  __shared__ float sw[160], sb[32];
  int tid=threadIdx.x;
  if(tid<160) sw[tid]=w[tid];
  if(tid<32)  sb[tid]=b[tid];
  __syncthreads();
  int pl = tid>>3, q = tid&7;
  int p = blockIdx.x*32 + pl;
  float i0=h[(size_t)p*2], i1=h[(size_t)p*2+1];
  float i2=x[(size_t)p*3], i3=x[(size_t)p*3+1], i4=x[(size_t)p*3+2];
  int c0=q*4;
  float4 o;
  float* po=(float*)&o;
  #pragma unroll
  for(int u=0;u<4;u++){
    int c=c0+u;
    po[u] = sb[c] + i0*sw[c] + i1*sw[32+c] + i2*sw[64+c] + i3*sw[96+c] + i4*sw[128+c];
  }
  ((float4*)V)[(size_t)p*8 + q] = o;
}

// ------- fused forward T+Y per (b,x): V slice -> F2 [bc*64+x][ky*8+kt] -------
// T-twiddles in REGISTERS (per-thread k row, 40 cplx); Y-twiddles read as
// float4 pairs (2 y at once). Cuts LDS instr per y from 104 to ~52 (was
// LDS-issue-bound at ~744 LDS-pipe cyc/y vs 352 VALU).
__global__ __launch_bounds__(256) void k_fwd_ty(const float* __restrict__ V, float2* __restrict__ F2){
  __shared__ __align__(16) unsigned char smem[61696];
  float*  vt    = (float*)smem;                 // 10240 floats (one 8-y group), 40960 B
  float2* f2out = (float2*)smem;                // alias (after last compute): 32*193 = 49408 B
  float2* twy   = (float2*)(smem + 49408);      // [ky][64 y] = 12288 B
  int tid = threadIdx.x;
  int b = blockIdx.x >> 6, x = blockIdx.x & 63;
  int c = tid & 31, k = tid >> 5;
  for(int i=tid;i<KYC*NY;i+=256){
    int ky=i/NY, y=i-ky*NY;
    int f = ky<M1C ? ky : ky+40;
    float ang = -TWO_PI*(float)((f*y)%NY)/(float)NY;
    twy[ky*NY+y] = make_float2(cosf(ang), sinf(ang));
  }
  // per-thread T-twiddle row (k fixed per thread)
  float2 twr[NT];
  #pragma unroll
  for(int t=0;t<NT;t++){
    float ang = -TWO_PI*(float)((k*t)%NT)/(float)NT;
    twr[t] = make_float2(cosf(ang), sinf(ang));
  }
  float2 acc[KYC];
  #pragma unroll
  for(int ky=0;ky<KYC;ky++) acc[ky]=make_float2(0.f,0.f);
  const float4* src = (const float4*)(V + (size_t)(b*NX+x)*(NY*NT*WID));
  for(int g=0; g<8; g++){
    __syncthreads();                       // prev compute / table init done
    #pragma unroll
    for(int r=0;r<10;r++) ((float4*)vt)[r*256+tid] = src[g*2560 + r*256 + tid];
    __syncthreads();
    for(int yl=0; yl<8; yl+=2){
      float sr0=0.f, si0=0.f, sr1=0.f, si1=0.f;
      const float* vp0 = vt + yl*1280 + c;
      const float* vp1 = vp0 + 1280;
      #pragma unroll
      for(int t=0;t<NT;t++){
        float2 w = twr[t];
        float v0 = vp0[t*32];              // 32 distinct addrs = all banks; upper half broadcast
        float v1 = vp1[t*32];
        sr0 += v0*w.x; si0 += v0*w.y;
        sr1 += v1*w.x; si1 += v1*w.y;
      }
      int y = g*8 + yl;
      #pragma unroll
      for(int ky=0;ky<KYC;ky++){
        float4 wy = *(const float4*)&twy[ky*NY + y];   // (w_y, w_{y+1}) one b128
        acc[ky].x += sr0*wy.x - si0*wy.y + sr1*wy.z - si1*wy.w;
        acc[ky].y += sr0*wy.y + si0*wy.x + sr1*wy.w + si1*wy.z;
      }
    }
  }
  __syncthreads();                         // vt dead -> f2out alias safe
  #pragma unroll
  for(int ky=0;ky<KYC;ky++) f2out[c*193 + ky*KT + k] = acc[ky];
  __syncthreads();
  for(int i=tid;i<WID*KYC*KT;i+=256){
    int cc=i/192, e=i-cc*192;
    F2[((size_t)(b*WID+cc)*NX + x)*(KYC*KT) + e] = f2out[cc*193 + e];
  }
}

// ---------------- forward X: F2 -> F3 [B,32,24,24,8] cplx ----------------
// twiddles interleaved as float2: 1 b64 read per MAC step (was 2 b32).
__global__ __launch_bounds__(256) void k_fwd_x(const float2* __restrict__ F2, float2* __restrict__ F3){
  __shared__ float2 tile[NX*KT];
  __shared__ float2 twi[KXC*65];          // stride 65 cplx
  int tid=threadIdx.x;
  int bc = blockIdx.x / KYC;
  int ky = blockIdx.x - bc*KYC;
  for(int i=tid;i<NX*KT;i+=256){
    int xx=i/KT, kt=i-xx*KT;
    tile[i] = F2[((size_t)bc*NX + xx)*(KYC*KT) + ky*KT + kt];
  }
  for(int i=tid;i<KXC*NX;i+=256){
    int kx=i/NX, xx=i-kx*NX;
    int f = kx<M1C ? kx : kx+40;
    float ang = -TWO_PI*(float)((f*xx)%NX)/(float)NX;
    twi[kx*65+xx] = make_float2(cosf(ang), sinf(ang));
  }
  __syncthreads();
  for(int item=tid; item<KXC*KT; item+=256){
    int kx=item/KT, kt=item-kx*KT;
    float sr=0.f, si=0.f;
    #pragma unroll 8
    for(int xx=0;xx<NX;xx++){
      float2 a = tile[xx*KT+kt];
      float2 w = twi[kx*65+xx];
      sr += a.x*w.x - a.y*w.y;
      si += a.x*w.y + a.y*w.x;
    }
    F3[(size_t)bc*(KXC*KYC*KT) + kx*(KYC*KT) + ky*KT + kt] = make_float2(sr,si);
  }
}

// ---------------- channel mix: F3 -> F4 ----------------
__global__ __launch_bounds__(256) void k_mix(const float2* __restrict__ F3, const float* __restrict__ wr,
                                             const float* __restrict__ wi, float2* __restrict__ F4){
  __shared__ float2 f3s[BATCH*WID*KT];     // [b][i][kt] = 16 KB
  int tid = threadIdx.x;
  int kx = blockIdx.x / KYC, ky = blockIdx.x - kx*KYC;
  int mode0 = blockIdx.x * KT;
  int xp = (kx>=M1C), yp = (ky>=M1C);
  int m1 = kx - M1C*xp, m2 = ky - M1C*yp;
  int blk = xp + 2*yp;
  for(int i=tid;i<1024;i+=256){
    int row=i>>2, q=i&3;
    ((float4*)f3s)[row*4+q] = ((const float4*)(F3 + (size_t)row*4608 + mode0))[q];
  }
  int o = tid>>3, kt = tid&7;
  size_t wbase = (size_t)blk*1179648 + (size_t)o*1152 + m1*96 + m2*8 + kt;
  float wre[WID], wim[WID];
  #pragma unroll
  for(int i=0;i<WID;i++){
    wre[i] = wr[wbase + (size_t)i*36864];
    wim[i] = wi[wbase + (size_t)i*36864];
  }
  __syncthreads();
  #pragma unroll
  for(int b=0;b<BATCH;b++){
    float ar=0.f, ai=0.f;
    #pragma unroll
    for(int i=0;i<WID;i++){
      float2 a = f3s[(b*WID+i)*KT + kt];
      ar += a.x*wre[i] - a.y*wim[i];
      ai += a.x*wim[i] + a.y*wre[i];
    }
    F4[(size_t)(b*WID+o)*4608 + mode0 + kt] = make_float2(ar,ai);
  }
}

// ---------------- inverse X: F4 -> F2 (1/64 folded) ----------------
// twiddles interleaved float2, stride 25 (2-way bank aliasing = free).
__global__ __launch_bounds__(256) void k_inv_x(const float2* __restrict__ F4, float2* __restrict__ F2){
  __shared__ float2 tile[KXC*KT];
  __shared__ float2 twi[NX*25];
  int tid=threadIdx.x;
  int bc = blockIdx.x / KYC, ky = blockIdx.x - (blockIdx.x/KYC)*KYC;
  for(int i=tid;i<KXC*KT;i+=256){
    int kx=i/KT, kt=i-kx*KT;
    tile[i] = F4[(size_t)bc*4608 + kx*(KYC*KT) + ky*KT + kt];
  }
  for(int i=tid;i<NX*KXC;i+=256){
    int xx=i/KXC, kx=i-xx*KXC;
    int f = kx<M1C ? kx : kx+40;
    float ang = TWO_PI*(float)((f*xx)%NX)/(float)NX;
    twi[xx*25+kx] = make_float2(cosf(ang)*(1.0f/64.0f), sinf(ang)*(1.0f/64.0f));
  }
  __syncthreads();
  for(int item=tid; item<NX*KT; item+=256){
    int xx=item/KT, kt=item-xx*KT;
    float sr=0.f, si=0.f;
    #pragma unroll 8
    for(int kx=0;kx<KXC;kx++){
      float2 a = tile[kx*KT+kt];
      float2 w = twi[xx*25+kx];
      sr += a.x*w.x - a.y*w.y;
      si += a.x*w.y + a.y*w.x;
    }
    F2[((size_t)bc*NX + xx)*(KYC*KT) + ky*KT + kt] = make_float2(sr,si);
  }
}

// ------- fused inv-Y + irfft-T + conv1x1 [+gelu], in-place on V -------
// grid = B*NX*2, block = (b, x, y-half). NOTE: no min-waves clamp — the kernel
// needs ~120 VGPRs (fr[24]c + wreg[32] + prefetch); clamping to (256,4) forced
// VGPR=64 and spilled fr/wreg to scratch = 1.3 GB/dispatch of fetch (R3-R5 bug).
//
// R6 restructure (LDS-pipe + barrier relief):
//  * tcts table DELETED: e^{i2pi k t/40} = e^{i pi k tg/4} (per-thread regs,
//    twtg[8]) * e^{i pi k j/20} (compile-time literal CJ/SJ). The (k==0?1:2)/40
//    scale is folded into fr at load. Removes 40 ds_read_b64 per thread per y.
//  * ftc double-buffered (fits in freed tcts space) -> ONE barrier per y
//    instead of two: barrier(y+1) already orders buffer reuse (no wave can
//    pass it until all waves finished conv(y)).
//  * conv k-loop outer / acc[5] inner keeps peak VGPR ~<=128 (4 waves/SIMD).
template<bool GELU>
__global__ __launch_bounds__(256) void k_conv(const float2* __restrict__ F2, const float* __restrict__ wcv,
                                              const float* __restrict__ bcv, float* __restrict__ V){
  __shared__ __align__(16) unsigned char smem[24576];
  float*  vt0  = (float*)smem;                  // 5120 B
  float*  vt1  = (float*)(smem+5120);           // 5120 B
  float2* ftc0 = (float2*)(smem+10240);         // 2048 B
  float2* ftc1 = (float2*)(smem+12288);         // 2048 B
  float2* twy  = (float2*)(smem+14336);         // 6144 B (end 20480)
  float2* f2h  = (float2*)smem;                 // prologue alias: 24576 B

  int tid=threadIdx.x;
  int b  = blockIdx.x >> 7;
  int x  = (blockIdx.x >> 1) & 63;
  int y0 = (blockIdx.x & 1) * 32;
  int cid = tid & 31, ktid = tid >> 5;   // inv-Y identity
  int oid = tid & 31, tg  = tid >> 5;    // conv identity; t = tg*5+j

  // ---- prologue: F2 slice -> registers via LDS (two halves) ----
  float2 fr[KYC];
  #pragma unroll
  for(int half=0; half<2; half++){
    for(int i=tid;i<1536;i+=256){
      int cc=i/96, q=i-cc*96;
      ((float4*)f2h)[i] = *((const float4*)(F2 + ((size_t)(b*WID + half*16 + cc)*NX + x)*(KYC*KT)) + q);
    }
    __syncthreads();
    if((cid>>4) == half){
      const float2* fp = f2h + (cid&15)*192 + ktid;
      #pragma unroll
      for(int ky=0;ky<KYC;ky++) fr[ky] = fp[ky*8];
    }
    __syncthreads();
  }
  // fold irfft-T scale (k==0?1:2)/NT into fr (linear through inv-Y)
  {
    float ts = (ktid==0 ? 1.0f : 2.0f) * (1.0f/(float)NT);
    #pragma unroll
    for(int ky=0;ky<KYC;ky++){ fr[ky].x *= ts; fr[ky].y *= ts; }
  }
  float wreg[WID];
  #pragma unroll
  for(int cc=0;cc<WID;cc++) wreg[cc] = wcv[oid*WID + cc];
  float breg = bcv[oid];
  // per-thread T-twiddle base: e^{i*pi/4*(k*tg mod 8)}  (t = 5*tg + j)
  float2 twtg[KT];
  #pragma unroll
  for(int k=0;k<KT;k++){
    float ang = 0.78539816339744831f*(float)((k*tg)&7);
    twtg[k] = make_float2(cosf(ang), sinf(ang));
  }
  for(int i=tid;i<32*KYC;i+=256){
    int yy=i/KYC, ky=i-yy*KYC;
    int f = ky<M1C ? ky : ky+40;
    float ang = TWO_PI*(float)((f*(y0+yy))%NY)/(float)NY;
    twy[i] = make_float2(cosf(ang)*(1.0f/64.0f), sinf(ang)*(1.0f/64.0f));
  }
  float* plane = V + (size_t)((b*NX+x)*NY + y0)*(NT*WID);
  const float4* gp = (const float4*)plane;
  bool has2 = tid < 64;
  float4 g0 = gp[tid];
  float4 g1 = has2 ? gp[256+tid] : make_float4(0,0,0,0);
  ((float4*)vt0)[tid] = g0;
  if(has2) ((float4*)vt0)[256+tid] = g1;
  __syncthreads();                        // publish vt0 + twy

  // cos/sin(pi*k*j/20) — compile-time literals (fold into v_fmac immediates)
  constexpr float CJ[KT][5] = {
    {1.f, 1.f,          1.f,          1.f,          1.f         },
    {1.f, 0.98768834f,  0.95105652f,  0.89100652f,  0.80901699f },
    {1.f, 0.95105652f,  0.80901699f,  0.58778525f,  0.30901699f },
    {1.f, 0.89100652f,  0.58778525f,  0.15643447f, -0.30901699f },
    {1.f, 0.80901699f,  0.30901699f, -0.30901699f, -0.80901699f },
    {1.f, 0.70710678f,  0.f,         -0.70710678f, -1.f         },
    {1.f, 0.58778525f, -0.30901699f, -0.95105652f, -0.80901699f },
    {1.f, 0.45399050f, -0.58778525f, -0.98768834f, -0.30901699f },
  };
  constexpr float SJ[KT][5] = {
    {0.f, 0.f,          0.f,          0.f,          0.f         },
    {0.f, 0.15643447f,  0.30901699f,  0.45399050f,  0.58778525f },
    {0.f, 0.30901699f,  0.58778525f,  0.80901699f,  0.95105652f },
    {0.f, 0.45399050f,  0.80901699f,  0.98768834f,  0.95105652f },
    {0.f, 0.58778525f,  0.95105652f,  0.95105652f,  0.58778525f },
    {0.f, 0.70710678f,  1.f,          0.70710678f,  0.f         },
    {0.f, 0.80901699f,  0.95105652f,  0.30901699f, -0.58778525f },
    {0.f, 0.89100652f,  0.80901699f, -0.15643447f, -0.95105652f },
  };

  for(int y=0;y<32;y++){
    if(y+1 < 32){                         // prefetch next plane (in flight across barrier)
      g0 = gp[(size_t)(y+1)*320 + tid];
      if(has2) g1 = gp[(size_t)(y+1)*320 + 256 + tid];
    }
    float2* ftcb = (y&1) ? ftc1 : ftc0;   // double-buffered transpose staging
    { // inverse-Y in registers -> ftcb[kt][c]
      const float2* tw = twy + y*KYC;
      float sr=0.f, si=0.f;
      #pragma unroll
      for(int ky=0;ky<KYC;ky++){
        float2 w = tw[ky];
        float2 a = fr[ky];
        sr += a.x*w.x - a.y*w.y;
        si += a.x*w.y + a.y*w.x;
      }
      ftcb[ktid*32 + cid] = make_float2(sr,si);
    }
    barrier_lds();                        // the ONLY barrier per y
    { // conv1x1 + irfft-T; direct full-line stores
      float acc[5];
      #pragma unroll
      for(int j=0;j<5;j++) acc[j] = breg;
      #pragma unroll
      for(int k=0;k<KT;k++){              // rotate mode by twtg, then literal DFT
        float2 f = ftcb[k*32 + oid];
        float gx = f.x*twtg[k].x - f.y*twtg[k].y;
        float gy = f.x*twtg[k].y + f.y*twtg[k].x;
        #pragma unroll
        for(int j=0;j<5;j++) acc[j] += gx*CJ[k][j] - gy*SJ[k][j];
      }
      const float* vb = (y&1) ? vt1 : vt0;
      float* outp = plane + (size_t)y*(NT*WID);
      #pragma unroll
      for(int j=0;j<5;j++){
        int t = tg*5 + j;
        float a = acc[j];
        const float* vrow = vb + t*32;
        #pragma unroll
        for(int c4=0;c4<WID;c4+=4){
          float4 vv = *(const float4*)(vrow + c4);   // broadcast b128
          a += vv.x*wreg[c4] + vv.y*wreg[c4+1] + vv.z*wreg[c4+2] + vv.w*wreg[c4+3];
        }
        outp[t*32 + oid] = GELU ? gelu_f(a) : a;     // lanes 0-31: one full 128B line
      }
    }
    if(y+1 < 32){                         // stage next plane into the other buffer
      float* d = (y&1) ? vt0 : vt1;
      ((float4*)d)[tid] = g0;
      if(has2) ((float4*)d)[256+tid] = g1;
    }
  }
}

// ---------------- fused fc1+gelu+fc2: V -> out [B,X,Y,T,2] ----------------
__global__ __launch_bounds__(256) void k_mlp(const float* __restrict__ V, const float* __restrict__ w1,
                                             const float* __restrict__ b1, const float* __restrict__ w2,
                                             const float* __restrict__ b2, float* __restrict__ out){
  __shared__ float sw1t[64*WID];          // [j][c]
  __shared__ float sb1[64], sw2[128], sb2[2];
  int tid=threadIdx.x;
  for(int i=tid;i<64*WID;i+=256){ int j=i>>5, c=i&31; sw1t[i]=w1[c*64+j]; }
  if(tid<64) sb1[tid]=b1[tid];
  if(tid<128) sw2[tid]=w2[tid];
  if(tid<2) sb2[tid]=b2[tid];
  __syncthreads();
  size_t p0 = (size_t)blockIdx.x*1024 + (size_t)tid*4;
  float vv[128];
  const float4* vp = (const float4*)(V + p0*WID);
  #pragma unroll
  for(int q=0;q<32;q++) *((float4*)(vv+4*q)) = vp[q];
  float oa[8];
  #pragma unroll
  for(int pt=0;pt<4;pt++){ oa[2*pt]=sb2[0]; oa[2*pt+1]=sb2[1]; }
  #pragma unroll 4
  for(int j=0;j<64;j++){
    float a0=sb1[j], a1=a0, a2=a0, a3=a0;
    const float* wrow = sw1t + j*WID;
    #pragma unroll
    for(int c4=0;c4<WID;c4+=4){
      float4 w = *(const float4*)(wrow + c4);        // broadcast b128
      a0 += vv[     c4]*w.x + vv[     c4+1]*w.y + vv[     c4+2]*w.z + vv[     c4+3]*w.w;
      a1 += vv[32 + c4]*w.x + vv[32 + c4+1]*w.y + vv[32 + c4+2]*w.z + vv[32 + c4+3]*w.w;
      a2 += vv[64 + c4]*w.x + vv[64 + c4+1]*w.y + vv[64 + c4+2]*w.z + vv[64 + c4+3]*w.w;
      a3 += vv[96 + c4]*w.x + vv[96 + c4+1]*w.y + vv[96 + c4+2]*w.z + vv[96 + c4+3]*w.w;
    }
    a0=gelu_f(a0); a1=gelu_f(a1); a2=gelu_f(a2); a3=gelu_f(a3);
    float u0=sw2[2*j], u1=sw2[2*j+1];
    oa[0]+=a0*u0; oa[1]+=a0*u1; oa[2]+=a1*u0; oa[3]+=a1*u1;
    oa[4]+=a2*u0; oa[5]+=a2*u1; oa[6]+=a3*u0; oa[7]+=a3*u1;
  }
  float4* op = (float4*)(out + p0*2);
  op[0]=make_float4(oa[0],oa[1],oa[2],oa[3]);
  op[1]=make_float4(oa[4],oa[5],oa[6],oa[7]);
}

extern "C" void kernel_launch(void* const* d_in, const int* in_sizes, int n_in,
                              void* d_out, int out_size, void* d_ws, size_t ws_size,
                              hipStream_t stream){
  const float* h     = (const float*)d_in[0];
  const float* x     = (const float*)d_in[1];
  const float* fc0_w = (const float*)d_in[2];
  const float* fc0_b = (const float*)d_in[3];
  const float* scwr[3] = {(const float*)d_in[4], (const float*)d_in[6], (const float*)d_in[8]};
  const float* scwi[3] = {(const float*)d_in[5], (const float*)d_in[7], (const float*)d_in[9]};
  const float* cw[3]   = {(const float*)d_in[10], (const float*)d_in[12], (const float*)d_in[14]};
  const float* cb[3]   = {(const float*)d_in[11], (const float*)d_in[13], (const float*)d_in[15]};
  const float* fc1_w = (const float*)d_in[16];
  const float* fc1_b = (const float*)d_in[17];
  const float* fc2_w = (const float*)d_in[18];
  const float* fc2_b = (const float*)d_in[19];

  // workspace: V (167.8 MB, layout [b,x,y,t,c]) | F2 (25.2 MB) | F4 (9.4 MB)
  // F3 lives in d_out (9.4 MB <= 10.5 MB) until k_mlp overwrites it.
  const size_t VSZ = (size_t)BATCH*WID*NXYT;
  float*  V  = (float*)d_ws;
  float2* F2 = (float2*)(V + VSZ);
  float2* F4 = F2 + (size_t)BATCH*WID*NX*KYC*KT;
  float2* F3 = (float2*)d_out;

  k_fc0<<<NP/32, 256, 0, stream>>>(h, x, fc0_w, fc0_b, V);
  for(int L=0; L<3; L++){
    k_fwd_ty<<<BATCH*NX, 256, 0, stream>>>(V, F2);
    k_fwd_x<<<(BATCH*WID)*KYC, 256, 0, stream>>>(F2, F3);
    k_mix<<<KXC*KYC, 256, 0, stream>>>(F3, scwr[L], scwi[L], F4);
    k_inv_x<<<(BATCH*WID)*KYC, 256, 0, stream>>>(F4, F2);
    if(L<2) k_conv<true ><<<BATCH*NX*2, 256, 0, stream>>>(F2, cw[L], cb[L], V);
    else    k_conv<false><<<BATCH*NX*2, 256, 0, stream>>>(F2, cw[L], cb[L], V);
  }
  k_mlp<<<NP/1024, 256, 0, stream>>>(V, fc1_w, fc1_b, fc2_w, fc2_b, (float*)d_out);
}